// Round 13
// baseline (748.469 us; speedup 1.0000x reference)
//
#include <hip/hip_runtime.h>
#include <hip/hip_bf16.h>
#include <math.h>

#define H_SIZE   1024
#define INTER    2048
#define NHEADS   32
#define HEAD_DIM 64
#define NSTATE   128
#define KCONV    4
#define CHUNK    256
#define CONV_DIM (INTER + 2*NSTATE)            // 2304
#define CIN_DIM  (CONV_DIM + NHEADS)           // 2336 (hBC + dt)
#define BATCH    2
#define SEQ      4096
#define MT       (BATCH*SEQ)                   // 8192
#define NC       (SEQ/CHUNK)                   // 16
#define EPS_F    1e-5f

typedef __attribute__((ext_vector_type(8))) short bf16x8;   // 8 bf16 in 4 VGPRs
typedef __attribute__((ext_vector_type(4))) float f32x4;
typedef unsigned short ushort_t;

__device__ __forceinline__ ushort_t f2bf(float x) {   // RNE float->bf16 bits
  unsigned u = __float_as_uint(x);
  u += 0x7fffu + ((u >> 16) & 1u);
  return (ushort_t)(u >> 16);
}
__device__ __forceinline__ float bf2f(ushort_t h) {
  return __uint_as_float((unsigned)h << 16);
}

// ---------------------------------------------------------------------------
// Split fp32 x into hi+lo bf16 planes: x ~= hi + lo (rel err ~2^-17).
// ---------------------------------------------------------------------------
__global__ __launch_bounds__(256) void convert_hl_kernel(
    const float* __restrict__ x, ushort_t* __restrict__ hi,
    ushort_t* __restrict__ lo, int n4) {
  int idx = blockIdx.x * 256 + threadIdx.x;
  int stride = gridDim.x * 256;
  for (int i = idx; i < n4; i += stride) {
    const float* p = x + (size_t)i * 4;
    float v0 = p[0], v1 = p[1], v2 = p[2], v3 = p[3];
    ushort_t h0 = f2bf(v0), h1 = f2bf(v1), h2 = f2bf(v2), h3 = f2bf(v3);
    ushort_t l0 = f2bf(v0 - bf2f(h0));
    ushort_t l1 = f2bf(v1 - bf2f(h1));
    ushort_t l2 = f2bf(v2 - bf2f(h2));
    ushort_t l3 = f2bf(v3 - bf2f(h3));
    *(uint2*)(hi + (size_t)i * 4) =
        make_uint2((unsigned)h0 | ((unsigned)h1 << 16), (unsigned)h2 | ((unsigned)h3 << 16));
    *(uint2*)(lo + (size_t)i * 4) =
        make_uint2((unsigned)l0 | ((unsigned)l1 << 16), (unsigned)l2 | ((unsigned)l3 << 16));
  }
}

// ---------------------------------------------------------------------------
// C[m,n] = sum_k A[m,k]*W[n,k] via split-bf16 MFMA.
// PLANES=3: Ah*Wh + Ah*Wl + Al*Wh.  PLANES=2: Ah*Wh + Ah*Wl.
// 128x128 tile, BK=32, 4 waves. 1D grid, bijective XCD chunking + G=4
// M-grouping. Output stride ldc decoupled from logical N.
// ---------------------------------------------------------------------------
#define LROW 40
template<int PLANES>
__global__ __launch_bounds__(256) void gemm_hl_mfma_kernel(
    const ushort_t* __restrict__ Ahi, const ushort_t* __restrict__ Alo,
    const ushort_t* __restrict__ Whi, const ushort_t* __restrict__ Wlo,
    float* __restrict__ C, int M, int N, int K, int nx, int ldc) {
  __shared__ __align__(16) ushort_t Ah[128*LROW];
  __shared__ __align__(16) ushort_t Al[(PLANES==3) ? 128*LROW : 8];
  __shared__ __align__(16) ushort_t Wh[128*LROW], Wl[128*LROW];
  const int tid = threadIdx.x;
  const int lane = tid & 63, wid = tid >> 6;
  const int wr = wid >> 1, wc = wid & 1;
  const int fr = lane & 15, fg = lane >> 4;

  const int cpx = gridDim.x >> 3;
  const int logical = (blockIdx.x & 7) * cpx + (blockIdx.x >> 3);
  const int grp = logical / (nx * 4);
  const int rem = logical - grp * (nx * 4);
  const int bx = rem >> 2;
  const int by = grp * 4 + (rem & 3);
  const int m0 = by * 128, n0 = bx * 128;

  const int r0 = tid >> 2;
  const int kseg = (tid & 3) * 8;
  const int r1 = r0 + 64;
  const size_t a0 = (size_t)(m0 + r0) * K + kseg;
  const size_t a1 = (size_t)(m0 + r1) * K + kseg;
  const size_t w0 = (size_t)(n0 + r0) * K + kseg;
  const size_t w1 = (size_t)(n0 + r1) * K + kseg;
  const bool wv0 = (n0 + r0) < N, wv1 = (n0 + r1) < N;

  bf16x8 gA0, gA1, gAl0, gAl1, gW0, gW1, gWl0, gWl1;
  const bf16x8 z8 = {};
  f32x4 acc[4][4] = {};

  auto glod = [&](int k0) {
    gA0  = *(const bf16x8*)(Ahi + a0 + k0);
    gA1  = *(const bf16x8*)(Ahi + a1 + k0);
    if constexpr (PLANES == 3) {
      gAl0 = *(const bf16x8*)(Alo + a0 + k0);
      gAl1 = *(const bf16x8*)(Alo + a1 + k0);
    }
    gW0  = wv0 ? *(const bf16x8*)(Whi + w0 + k0) : z8;
    gW1  = wv1 ? *(const bf16x8*)(Whi + w1 + k0) : z8;
    gWl0 = wv0 ? *(const bf16x8*)(Wlo + w0 + k0) : z8;
    gWl1 = wv1 ? *(const bf16x8*)(Wlo + w1 + k0) : z8;
  };

  glod(0);
  for (int k0 = 0; k0 < K; k0 += 32) {
    __syncthreads();
    *(bf16x8*)&Ah[r0*LROW + kseg] = gA0;
    *(bf16x8*)&Ah[r1*LROW + kseg] = gA1;
    if constexpr (PLANES == 3) {
      *(bf16x8*)&Al[r0*LROW + kseg] = gAl0;
      *(bf16x8*)&Al[r1*LROW + kseg] = gAl1;
    }
    *(bf16x8*)&Wh[r0*LROW + kseg] = gW0;
    *(bf16x8*)&Wh[r1*LROW + kseg] = gW1;
    *(bf16x8*)&Wl[r0*LROW + kseg] = gWl0;
    *(bf16x8*)&Wl[r1*LROW + kseg] = gWl1;
    __syncthreads();
    if (k0 + 32 < K) glod(k0 + 32);

    bf16x8 wh[4], wl[4];
#pragma unroll
    for (int nf = 0; nf < 4; ++nf) {
      int off = (wc*64 + nf*16 + fr) * LROW + 8*fg;
      wh[nf] = *(const bf16x8*)&Wh[off];
      wl[nf] = *(const bf16x8*)&Wl[off];
    }
#pragma unroll
    for (int mf = 0; mf < 4; ++mf) {
      int aoff = (wr*64 + mf*16 + fr) * LROW + 8*fg;
      bf16x8 ah = *(const bf16x8*)&Ah[aoff];
      bf16x8 al;
      if constexpr (PLANES == 3) al = *(const bf16x8*)&Al[aoff];
#pragma unroll
      for (int nf = 0; nf < 4; ++nf) {
        acc[mf][nf] = __builtin_amdgcn_mfma_f32_16x16x32_bf16(ah, wh[nf], acc[mf][nf], 0, 0, 0);
        acc[mf][nf] = __builtin_amdgcn_mfma_f32_16x16x32_bf16(ah, wl[nf], acc[mf][nf], 0, 0, 0);
        if constexpr (PLANES == 3)
          acc[mf][nf] = __builtin_amdgcn_mfma_f32_16x16x32_bf16(al, wh[nf], acc[mf][nf], 0, 0, 0);
      }
    }
  }

#pragma unroll
  for (int mf = 0; mf < 4; ++mf)
#pragma unroll
    for (int nf = 0; nf < 4; ++nf) {
      int col = n0 + wc*64 + nf*16 + fr;
      if (col < N) {
        size_t base = (size_t)(m0 + wr*64 + mf*16 + fg*4) * ldc + col;
        f32x4 v = acc[mf][nf];
        C[base]                 = v[0];
        C[base + (size_t)ldc]   = v[1];
        C[base + 2*(size_t)ldc] = v[2];
        C[base + 3*(size_t)ldc] = v[3];
      }
    }
}

// ---------------------------------------------------------------------------
// Causal conv (K=4) + bias + SiLU, sliding window, 32-row tiles.
// x channels (c<2048)  -> TRANSPOSED bf16 hi/lo planes xT[p][row] (64B writes)
// B/C channels         -> row-major bf16 hi/lo planes (as before)
// ---------------------------------------------------------------------------
__global__ __launch_bounds__(256) void conv2_kernel(
    const float* __restrict__ cin, const float* __restrict__ cw,
    const float* __restrict__ cb, ushort_t* __restrict__ xTh,
    ushort_t* __restrict__ xTl, ushort_t* __restrict__ Bph,
    ushort_t* __restrict__ Bpl, ushort_t* __restrict__ Cph,
    ushort_t* __restrict__ Cpl) {
  const int c = blockIdx.x * 256 + threadIdx.x;   // 0..2303
  const int r0 = blockIdx.y * 32;
  const int s0 = r0 & (SEQ - 1);
  const float w0 = cw[c*KCONV+0], w1 = cw[c*KCONV+1];
  const float w2 = cw[c*KCONV+2], w3 = cw[c*KCONV+3];
  const float bias = cb[c];
  const float* cp = cin + (size_t)r0 * CIN_DIM + c;
  float xm3 = (s0 > 0) ? cp[-3*CIN_DIM] : 0.f;
  float xm2 = (s0 > 0) ? cp[-2*CIN_DIM] : 0.f;
  float xm1 = (s0 > 0) ? cp[-1*CIN_DIM] : 0.f;

  if (c < INTER) {
    ushort_t hb[32], lb[32];
#pragma unroll
    for (int i = 0; i < 32; ++i) {
      float x0 = cp[(size_t)i * CIN_DIM];
      float acc = fmaf(w0, xm3, fmaf(w1, xm2, fmaf(w2, xm1, fmaf(w3, x0, bias))));
      acc = acc / (1.f + expf(-acc));  // silu
      ushort_t hh = f2bf(acc);
      hb[i] = hh; lb[i] = f2bf(acc - bf2f(hh));
      xm3 = xm2; xm2 = xm1; xm1 = x0;
    }
    ushort_t* ph = xTh + (size_t)c * MT + r0;
    ushort_t* pl = xTl + (size_t)c * MT + r0;
#pragma unroll
    for (int j = 0; j < 4; ++j) {
      bf16x8 vh, vl;
#pragma unroll
      for (int k = 0; k < 8; ++k) { vh[k] = (short)hb[j*8+k]; vl[k] = (short)lb[j*8+k]; }
      *(bf16x8*)(ph + j*8) = vh;
      *(bf16x8*)(pl + j*8) = vl;
    }
  } else {
    const int cc = c - INTER;
#pragma unroll
    for (int i = 0; i < 32; ++i) {
      float x0 = cp[(size_t)i * CIN_DIM];
      float acc = fmaf(w0, xm3, fmaf(w1, xm2, fmaf(w2, xm1, fmaf(w3, x0, bias))));
      acc = acc / (1.f + expf(-acc));  // silu
      size_t row = (size_t)(r0 + i);
      ushort_t hh = f2bf(acc);
      ushort_t ll = f2bf(acc - bf2f(hh));
      if (cc < NSTATE) { Bph[row*NSTATE + cc] = hh; Bpl[row*NSTATE + cc] = ll; }
      else { Cph[row*NSTATE + (cc-NSTATE)] = hh; Cpl[row*NSTATE + (cc-NSTATE)] = ll; }
      xm3 = xm2; xm2 = xm1; xm1 = x0;
    }
  }
}

// ---------------------------------------------------------------------------
// Per (b,h,chunk): dt = softplus(cin_dt + dt_bias) -> dtp; a = dt*A;
// inclusive cumsum -> acum; g = exp(last).
// ---------------------------------------------------------------------------
__global__ __launch_bounds__(256) void cumsum_kernel(
    const float* __restrict__ cin, const float* __restrict__ A_log,
    const float* __restrict__ dtb, float* __restrict__ dtp,
    float* __restrict__ acum, float* __restrict__ gch) {
  const int c = blockIdx.x, h = blockIdx.y, b = blockIdx.z;
  const int tid = threadIdx.x;
  __shared__ float sm[CHUNK];
  const float A = -expf(A_log[h]);
  const int s = c * CHUNK + tid;
  const size_t row = (size_t)(b*SEQ + s);
  float draw = cin[row*CIN_DIM + CONV_DIM + h] + dtb[h];
  float d = (draw > 20.f) ? draw : log1pf(expf(draw));   // softplus
  dtp[row*NHEADS + h] = d;
  float a = d * A;
  sm[tid] = a;
  __syncthreads();
  for (int off = 1; off < CHUNK; off <<= 1) {
    float v = 0.f;
    if (tid >= off) v = sm[tid - off];
    __syncthreads();
    sm[tid] += v;
    __syncthreads();
  }
  float ac = sm[tid];
  acum[((size_t)(b*NHEADS + h)*NC + c)*CHUNK + tid] = ac;
  if (tid == CHUNK-1) gch[(size_t)(b*NHEADS + h)*NC + c] = expf(ac);
}

// ---------------------------------------------------------------------------
// Yd via MFMA, per (b, c, lt, h). C frags in regs; B in LDS; X fragments
// loaded DIRECTLY from global xT planes (dt folded into stage-2 G).
// LDS ~52.8 KB -> 3 blocks/CU.
// ---------------------------------------------------------------------------
#define CBROW 136
#define GROW  72
__global__ __launch_bounds__(256) void yd_mfma_kernel(
    const ushort_t* __restrict__ Bph, const ushort_t* __restrict__ Bpl,
    const ushort_t* __restrict__ Cph, const ushort_t* __restrict__ Cpl,
    const ushort_t* __restrict__ xTh, const ushort_t* __restrict__ xTl,
    const float* __restrict__ acum, const float* __restrict__ dtp,
    const float* __restrict__ Dv, float* __restrict__ y) {
  __shared__ __align__(16) ushort_t BhS[64*CBROW], BlS[64*CBROW];
  __shared__ __align__(16) ushort_t GhS[4][16*GROW], GlS[4][16*GROW];
  __shared__ float acLs[64], acSs[64], dtSs[64];

  const int h = blockIdx.x;
  const int c = blockIdx.y >> 2, lt = blockIdx.y & 3;
  const int b = blockIdx.z;
  const int tid = threadIdx.x;
  const int lane = tid & 63, w = tid >> 6;
  const int fr = lane & 15, fg = lane >> 4;

  const size_t seqbase = (size_t)(b*SEQ + c*CHUNK);
  const size_t acbase  = ((size_t)(b*NHEADS + h)*NC + c)*CHUNK;

  bf16x8 cfh[4], cfl[4];
  {
    const size_t cg = (seqbase + lt*64 + w*16 + fr) * 128;
#pragma unroll
    for (int ks = 0; ks < 4; ++ks) {
      int ko = ks*32 + fg*8;
      cfh[ks] = *(const bf16x8*)(Cph + cg + ko);
      cfl[ks] = *(const bf16x8*)(Cpl + cg + ko);
    }
  }
  if (tid < 64) acLs[tid] = acum[acbase + lt*64 + tid];

  f32x4 acc[4] = {};

  for (int st = 0; st <= lt; ++st) {
    __syncthreads();
    {
      const size_t g0 = (seqbase + st*64) * 128;
#pragma unroll
      for (int i = 0; i < 4; ++i) {
        int f = tid + 256*i; int r = f >> 4; int k8 = (f & 15) * 8;
        *(bf16x8*)&BhS[r*CBROW + k8] = *(const bf16x8*)(Bph + g0 + (size_t)r*128 + k8);
        *(bf16x8*)&BlS[r*CBROW + k8] = *(const bf16x8*)(Bpl + g0 + (size_t)r*128 + k8);
      }
    }
    if (tid < 64) acSs[tid] = acum[acbase + st*64 + tid];
    else if (tid < 128) dtSs[tid-64] = dtp[(seqbase + st*64 + (tid-64))*NHEADS + h];
    __syncthreads();

    // stage1: G(16x64 strip) = C · B^T, K=128, 3 planes
    f32x4 g[4] = {};
#pragma unroll
    for (int ks = 0; ks < 4; ++ks) {
      const int ko = ks*32 + fg*8;
#pragma unroll
      for (int nf = 0; nf < 4; ++nf) {
        const int rb = (nf*16 + fr) * CBROW + ko;
        bf16x8 bh = *(const bf16x8*)&BhS[rb];
        bf16x8 bl = *(const bf16x8*)&BlS[rb];
        g[nf] = __builtin_amdgcn_mfma_f32_16x16x32_bf16(cfh[ks], bh, g[nf], 0, 0, 0);
        g[nf] = __builtin_amdgcn_mfma_f32_16x16x32_bf16(cfh[ks], bl, g[nf], 0, 0, 0);
        g[nf] = __builtin_amdgcn_mfma_f32_16x16x32_bf16(cfl[ks], bh, g[nf], 0, 0, 0);
      }
    }
    // stage2: mask + decay + dt[s] on C/D frags (col=fr, row=fg*4+r)
    {
      const bool full = (st < lt);
#pragma unroll
      for (int nf = 0; nf < 4; ++nf) {
        int sl = nf*16 + fr;
        float aS = acSs[sl];
        float dS = dtSs[sl];
#pragma unroll
        for (int r = 0; r < 4; ++r) {
          int ll = w*16 + fg*4 + r;
          float v = 0.f;
          if (full || ll >= sl) v = g[nf][r] * __expf(acLs[ll] - aS) * dS;
          ushort_t hh = f2bf(v);
          ushort_t lo2 = f2bf(v - bf2f(hh));
          GhS[w][(fg*4 + r)*GROW + sl] = hh;
          GlS[w][(fg*4 + r)*GROW + sl] = lo2;
        }
      }
    }
    __syncthreads();
    // stage3: acc += G(16x64) · X^T, X frags straight from global xT planes
#pragma unroll
    for (int ks = 0; ks < 2; ++ks) {
      const int ko = ks*32 + fg*8;
      bf16x8 gh = *(const bf16x8*)&GhS[w][fr*GROW + ko];
      bf16x8 gl = *(const bf16x8*)&GlS[w][fr*GROW + ko];
#pragma unroll
      for (int nf = 0; nf < 4; ++nf) {
        const size_t xb = (size_t)(h*HEAD_DIM + nf*16 + fr) * MT + seqbase + st*64 + ko;
        bf16x8 xh = *(const bf16x8*)(xTh + xb);
        bf16x8 xl = *(const bf16x8*)(xTl + xb);
        acc[nf] = __builtin_amdgcn_mfma_f32_16x16x32_bf16(gh, xh, acc[nf], 0, 0, 0);
        acc[nf] = __builtin_amdgcn_mfma_f32_16x16x32_bf16(gh, xl, acc[nf], 0, 0, 0);
        acc[nf] = __builtin_amdgcn_mfma_f32_16x16x32_bf16(gl, xh, acc[nf], 0, 0, 0);
      }
    }
  }

  // epilogue: + D*x (x reconstructed from planes), store
  const float Dh = Dv[h];
#pragma unroll
  for (int nf = 0; nf < 4; ++nf) {
    int p = nf*16 + fr;
    const size_t xrow0 = (size_t)(h*HEAD_DIM + p) * MT + seqbase + lt*64 + w*16 + fg*4;
#pragma unroll
    for (int r = 0; r < 4; ++r) {
      size_t row = seqbase + lt*64 + w*16 + fg*4 + r;
      float xval = bf2f(xTh[xrow0 + r]) + bf2f(xTl[xrow0 + r]);
      y[row*INTER + h*HEAD_DIM + p] = acc[nf][r] + Dh * xval;
    }
  }
}

// ---------------------------------------------------------------------------
// states via MFMA, per (b,c,h): states[p,n] = sum_l x[l,p]·(mult[l]·B[l,n]).
// A-operand (x^T) straight from global planes; mult folded into B^T staging.
// LDS 36 KB -> 4 blocks/CU.
// ---------------------------------------------------------------------------
#define SXROW 72
__global__ __launch_bounds__(256) void states_mfma_kernel(
    const ushort_t* __restrict__ Bph, const ushort_t* __restrict__ Bpl,
    const ushort_t* __restrict__ xTh, const ushort_t* __restrict__ xTl,
    const float* __restrict__ acum, const float* __restrict__ dtp,
    float* __restrict__ states) {
  __shared__ __align__(16) ushort_t BhS[128*SXROW], BlS[128*SXROW]; // [n][l]
  const int h = blockIdx.x, c = blockIdx.y, b = blockIdx.z;
  const int tid = threadIdx.x;
  const int lane = tid & 63, w = tid >> 6;
  const int fr = lane & 15, fg = lane >> 4;
  const size_t seqbase = (size_t)(b*SEQ + c*CHUNK);
  const size_t acbase  = ((size_t)(b*NHEADS + h)*NC + c)*CHUNK;
  const float aclast = acum[acbase + CHUNK - 1];
  f32x4 acc[8] = {};

  for (int lt = 0; lt < 4; ++lt) {
    __syncthreads();
    // stage B'[n][l] = mult[l]*(Bh+Bl)[l][n], re-split, transposed+swizzled
#pragma unroll
    for (int i = 0; i < 4; ++i) {
      int f = tid + 256*i; int l = f >> 4; int n8 = (f & 15) * 8;
      size_t row = seqbase + lt*64 + l;
      float mult = dtp[row*NHEADS + h] * __expf(aclast - acum[acbase + lt*64 + l]);
      size_t g0 = row * 128 + n8;
      bf16x8 bh = *(const bf16x8*)(Bph + g0);
      bf16x8 bl = *(const bf16x8*)(Bpl + g0);
#pragma unroll
      for (int j = 0; j < 8; ++j) {
        int n = n8 + j;
        int sw = l ^ (((n >> 2) & 7) << 3);
        float bv = (bf2f((ushort_t)bh[j]) + bf2f((ushort_t)bl[j])) * mult;
        ushort_t hh = f2bf(bv);
        BhS[n*SXROW + sw] = hh;
        BlS[n*SXROW + sw] = f2bf(bv - bf2f(hh));
      }
    }
    __syncthreads();
#pragma unroll
    for (int ks = 0; ks < 2; ++ks) {
      const int ko = ks*32 + fg*8;
      const size_t xb = (size_t)(h*HEAD_DIM + w*16 + fr) * MT + seqbase + lt*64 + ko;
      bf16x8 ah = *(const bf16x8*)(xTh + xb);
      bf16x8 al = *(const bf16x8*)(xTl + xb);
#pragma unroll
      for (int nf = 0; nf < 8; ++nf) {
        const int nb = nf*16 + fr;
        const int kb = ko ^ (((nb >> 2) & 7) << 3);
        bf16x8 bh = *(const bf16x8*)&BhS[nb*SXROW + kb];
        bf16x8 bl = *(const bf16x8*)&BlS[nb*SXROW + kb];
        acc[nf] = __builtin_amdgcn_mfma_f32_16x16x32_bf16(ah, bh, acc[nf], 0, 0, 0);
        acc[nf] = __builtin_amdgcn_mfma_f32_16x16x32_bf16(ah, bl, acc[nf], 0, 0, 0);
        acc[nf] = __builtin_amdgcn_mfma_f32_16x16x32_bf16(al, bh, acc[nf], 0, 0, 0);
      }
    }
  }
  float* sp = states + ((size_t)(b*NC + c)*NHEADS + h)*HEAD_DIM*NSTATE;
#pragma unroll
  for (int nf = 0; nf < 8; ++nf) {
    int n = nf*16 + fr;
#pragma unroll
    for (int r = 0; r < 4; ++r) {
      int p = w*16 + fg*4 + r;
      sp[(size_t)p*NSTATE + n] = acc[nf][r];
    }
  }
}

// ---------------------------------------------------------------------------
// Inter-chunk scan, IN PLACE, 1024 threads. Writes the carry (state BEFORE
// chunk c) as split-bf16 hi/lo planes into the same 32KB block.
// ---------------------------------------------------------------------------
__global__ __launch_bounds__(1024) void scan_kernel(
    float* __restrict__ st, const float* __restrict__ g) {
  const int bh = blockIdx.x;
  const int b = bh >> 5, h = bh & 31;
  const int tid = threadIdx.x;
  float carry[8];
#pragma unroll
  for (int i = 0; i < 8; ++i) carry[i] = 0.f;
  for (int c = 0; c < NC; ++c) {
    const float gc = g[(size_t)(b*NHEADS + h)*NC + c];
    float* base = st + ((size_t)(b*NC + c)*NHEADS + h)*HEAD_DIM*NSTATE;
    ushort_t* ub = (ushort_t*)base;
    float sv[8];
#pragma unroll
    for (int i = 0; i < 8; ++i) sv[i] = base[i*1024 + tid];
    __syncthreads();
#pragma unroll
    for (int i = 0; i < 8; ++i) {
      int e = i*1024 + tid;
      ushort_t hh = f2bf(carry[i]);
      ub[e]        = hh;
      ub[8192 + e] = f2bf(carry[i] - bf2f(hh));
      carry[i] = fmaf(carry[i], gc, sv[i]);
    }
  }
}

// ---------------------------------------------------------------------------
// Yo via MFMA, per (b,c,h): y[l,p] += exp(acum[l]) * sum_n C[l,n]*prev[p,n].
// ---------------------------------------------------------------------------
#define PROW 136
__global__ __launch_bounds__(256) void yo_mfma_kernel(
    const ushort_t* __restrict__ Cph, const ushort_t* __restrict__ Cpl,
    const ushort_t* __restrict__ stp, const float* __restrict__ acum,
    float* __restrict__ y) {
  __shared__ __align__(16) ushort_t PhS[64*PROW], PlS[64*PROW];
  const int h = blockIdx.x, c = blockIdx.y, b = blockIdx.z;
  const int tid = threadIdx.x;
  const int lane = tid & 63, w = tid >> 6;
  const int fr = lane & 15, fg = lane >> 4;
  const size_t seqbase = (size_t)(b*SEQ + c*CHUNK);
  const size_t acbase  = ((size_t)(b*NHEADS + h)*NC + c)*CHUNK;

  const ushort_t* pb = stp + ((size_t)(b*NC + c)*NHEADS + h) * (size_t)(2*HEAD_DIM*NSTATE);
#pragma unroll
  for (int i = 0; i < 4; ++i) {
    int f = tid + 256*i; int r = f >> 4; int k8 = (f & 15) * 8;
    *(bf16x8*)&PhS[r*PROW + k8] = *(const bf16x8*)(pb + (size_t)r*128 + k8);
    *(bf16x8*)&PlS[r*PROW + k8] = *(const bf16x8*)(pb + 8192 + (size_t)r*128 + k8);
  }
  __syncthreads();

  for (int lt = 0; lt < 4; ++lt) {
    const size_t cg = (seqbase + lt*64 + w*16 + fr) * 128;
    f32x4 acc[4] = {};
#pragma unroll
    for (int ks = 0; ks < 4; ++ks) {
      int ko = ks*32 + fg*8;
      bf16x8 ah = *(const bf16x8*)(Cph + cg + ko);
      bf16x8 al = *(const bf16x8*)(Cpl + cg + ko);
#pragma unroll
      for (int nf = 0; nf < 4; ++nf) {
        const int rb = (nf*16 + fr) * PROW + ko;
        bf16x8 bh = *(const bf16x8*)&PhS[rb];
        bf16x8 bl = *(const bf16x8*)&PlS[rb];
        acc[nf] = __builtin_amdgcn_mfma_f32_16x16x32_bf16(ah, bh, acc[nf], 0, 0, 0);
        acc[nf] = __builtin_amdgcn_mfma_f32_16x16x32_bf16(ah, bl, acc[nf], 0, 0, 0);
        acc[nf] = __builtin_amdgcn_mfma_f32_16x16x32_bf16(al, bh, acc[nf], 0, 0, 0);
      }
    }
#pragma unroll
    for (int r = 0; r < 4; ++r) {
      int lrow = lt*64 + w*16 + fg*4 + r;
      float e = __expf(acum[acbase + lrow]);
      float* yrow = y + (seqbase + lrow)*INTER + h*HEAD_DIM;
#pragma unroll
      for (int nf = 0; nf < 4; ++nf) {
        int p = nf*16 + fr;
        yrow[p] += e * acc[nf][r];
      }
    }
  }
}

// ---------------------------------------------------------------------------
// Gated RMSNorm, fused bf16-hi output (feeds 2-plane out_proj).
// ---------------------------------------------------------------------------
__global__ __launch_bounds__(256) void rms_kernel(
    const float* __restrict__ y, const float* __restrict__ gate,
    const float* __restrict__ norm_w, ushort_t* __restrict__ yh) {
  const int bs = blockIdx.x;
  const int tid = threadIdx.x;
  const float* yrow = y + (size_t)bs * INTER;
  const float* grow = gate + (size_t)bs * INTER;
  float yf[8];
  float ss = 0.f;
#pragma unroll
  for (int i = 0; i < 8; ++i) {
    int c = tid + i*256;
    float v = yrow[c];
    float gt = grow[c];
    float f = v * (gt / (1.f + expf(-gt)));
    yf[i] = f;
    ss += f*f;
  }
#pragma unroll
  for (int off = 32; off >= 1; off >>= 1) ss += __shfl_xor(ss, off, 64);
  __shared__ float red[4];
  if ((tid & 63) == 0) red[tid >> 6] = ss;
  __syncthreads();
  float total = red[0] + red[1] + red[2] + red[3];
  float sc = rsqrtf(total * (1.f/INTER) + EPS_F);
#pragma unroll
  for (int i = 0; i < 8; ++i) {
    int c = tid + i*256;
    yh[(size_t)bs*INTER + c] = f2bf(norm_w[c] * yf[i] * sc);
  }
}

__global__ void zero_kernel(float* p, size_t n) {
  size_t i = (size_t)blockIdx.x * blockDim.x + threadIdx.x;
  if (i < n) p[i] = 0.f;
}

// ---------------------------------------------------------------------------
extern "C" void kernel_launch(void* const* d_in, const int* in_sizes, int n_in,
                              void* d_out, int out_size, void* d_ws, size_t ws_size,
                              hipStream_t stream) {
  const float* hidden = (const float*)d_in[0];
  const float* in_w   = (const float*)d_in[1];
  const float* conv_w = (const float*)d_in[2];
  const float* conv_b = (const float*)d_in[3];
  const float* dt_b   = (const float*)d_in[4];
  const float* A_log  = (const float*)d_in[5];
  const float* Dv     = (const float*)d_in[6];
  const float* norm_w = (const float*)d_in[7];
  const float* out_w  = (const float*)d_in[8];
  float* out = (float*)d_out;

  const int M = MT;

  const size_t sz_cin  = (size_t)M * CIN_DIM;
  const size_t sz_hbc  = (size_t)M * CONV_DIM;   // region reused for xT planes / gate / wplh
  const size_t sz_dtp  = (size_t)M * NHEADS;
  const size_t sz_acum = (size_t)BATCH*NHEADS*NC*CHUNK;
  const size_t sz_gch  = (size_t)BATCH*NHEADS*NC;
  const size_t sz_R    = (size_t)BATCH*NC*NHEADS*HEAD_DIM*NSTATE;
  const size_t need = (sz_cin + sz_hbc + sz_dtp + sz_acum + sz_gch + sz_R) * sizeof(float);

  if (ws_size < need) {
    size_t n = (size_t)out_size;
    zero_kernel<<<(unsigned)((n + 255) / 256), 256, 0, stream>>>(out, n);
    return;
  }

  float* ws = (float*)d_ws;
  size_t o = 0;
  float* cin  = ws + o; o += sz_cin;
  float* hbc  = ws + o; o += sz_hbc;
  float* dtp  = ws + o; o += sz_dtp;
  float* acum = ws + o; o += sz_acum;
  float* gch  = ws + o; o += sz_gch;
  float* R    = ws + o; o += sz_R;

  float* y    = cin;   // cin dead (as conv/cumsum input) after step 3
  float* gate = hbc;   // xT planes dead after step 5; gate reuses region
  float* st   = R;

  ushort_t* xTh = (ushort_t*)hbc;                   // 2048 x 8192 ush (33.55 MB)
  ushort_t* xTl = xTh + (size_t)INTER * MT;         // +33.55 MB (region 75.5 MB)

  ushort_t* hidhi = (ushort_t*)R;
  ushort_t* hidlo = hidhi + (size_t)M * H_SIZE;
  ushort_t* yhR   = (ushort_t*)R;        // rms output hi-plane (R dead after yo)
  ushort_t* wplh  = (ushort_t*)hbc;      // step-10 weight planes (hbc dead after rms)

  // d_out scratch: weights at offset 0 (steps 1,8); B/C bf16 planes at +16MB
  ushort_t* wscr = (ushort_t*)out;
  const size_t MP = (size_t)M * 128;
  ushort_t* bcp  = (ushort_t*)((char*)d_out + (size_t)(16u << 20));
  ushort_t* Bph = bcp;
  ushort_t* Bpl = bcp + MP;
  ushort_t* Cph = bcp + 2*MP;
  ushort_t* Cpl = bcp + 3*MP;

  // 1) in_proj conv-input columns, precision routed per consumer
  {
    int nA4 = (M * H_SIZE) / 4;
    int nW  = CIN_DIM * H_SIZE;
    convert_hl_kernel<<<2048, 256, 0, stream>>>(hidden, hidhi, hidlo, nA4);
    convert_hl_kernel<<<2048, 256, 0, stream>>>(in_w + (size_t)INTER*H_SIZE, wscr, wscr + nW, nW/4);
    gemm_hl_mfma_kernel<2><<<16 * (M/128), 256, 0, stream>>>(
        hidhi, hidlo, wscr, wscr + nW, cin, M, 2048, H_SIZE, 16, CIN_DIM);
    gemm_hl_mfma_kernel<3><<<3 * (M/128), 256, 0, stream>>>(
        hidhi, hidlo, wscr + (size_t)2048*H_SIZE, wscr + nW + (size_t)2048*H_SIZE,
        cin + 2048, M, 288, H_SIZE, 3, CIN_DIM);
  }
  // 2) causal conv + SiLU; x -> transposed bf16 planes, B/C -> row planes
  conv2_kernel<<<dim3(CONV_DIM/256, M/32), 256, 0, stream>>>(
      cin, conv_w, conv_b, xTh, xTl, Bph, Bpl, Cph, Cpl);
  // 3) softplus(dt)+cumsum (reads raw dt from cin tail cols)
  cumsum_kernel<<<dim3(NC, NHEADS, BATCH), 256, 0, stream>>>(
      cin, A_log, dt_b, dtp, acum, gch);
  // 4) intra-chunk Yd + D*x -> y  (MFMA; X from global xT)
  yd_mfma_kernel<<<dim3(NHEADS, NC*4, BATCH), 256, 0, stream>>>(
      Bph, Bpl, Cph, Cpl, xTh, xTl, acum, dtp, Dv, y);
  // 5) chunk states -> st  (MFMA; A from global xT, mult folded into B)
  states_mfma_kernel<<<dim3(NHEADS, NC, BATCH), 256, 0, stream>>>(
      Bph, Bpl, xTh, xTl, acum, dtp, st);
  // 6) inter-chunk scan; prev written as split-bf16 planes in place
  scan_kernel<<<dim3(BATCH*NHEADS), 1024, 0, stream>>>(st, gch);
  // 7) inter-chunk Yo -> y (+=)  (MFMA)
  yo_mfma_kernel<<<dim3(NHEADS, NC, BATCH), 256, 0, stream>>>(
      Cph, Cpl, (const ushort_t*)st, acum, y);
  // 8) gate columns of in_proj (2-plane); st dead, reconvert hidden into R
  {
    int nA4 = (M * H_SIZE) / 4;
    int nW  = INTER * H_SIZE;
    convert_hl_kernel<<<2048, 256, 0, stream>>>(hidden, hidhi, hidlo, nA4);
    convert_hl_kernel<<<2048, 256, 0, stream>>>(in_w, wscr, wscr + nW, nW/4);
    gemm_hl_mfma_kernel<2><<<16 * (M/128), 256, 0, stream>>>(
        hidhi, hidlo, wscr, wscr + nW, gate, M, INTER, H_SIZE, 16, INTER);
  }
  // 9) gated RMSNorm: y,gate -> bf16 hi plane in R
  rms_kernel<<<dim3(M), 256, 0, stream>>>(y, gate, norm_w, yhR);
  // 10) out_proj (2-plane on A=yh; weight planes in hbc region)
  {
    int nW  = H_SIZE * INTER;
    convert_hl_kernel<<<2048, 256, 0, stream>>>(out_w, wplh, wplh + nW, nW/4);
    gemm_hl_mfma_kernel<2><<<8 * (M/128), 256, 0, stream>>>(
        yhR, yhR, wplh, wplh + nW, out, M, H_SIZE, INTER, 8, H_SIZE);
  }
}